// Round 2
// baseline (2527.691 us; speedup 1.0000x reference)
//
#include <hip/hip_runtime.h>
#include <hip/hip_bf16.h>

typedef __attribute__((ext_vector_type(4))) float f32x4;
typedef __attribute__((ext_vector_type(8))) _Float16 f16x8;

static __device__ __forceinline__ unsigned short h2u(_Float16 h) {
  union { _Float16 h; unsigned short u; } v; v.h = h; return v.u;
}

// ---------------- init kernels ----------------

// fp32 -> fp16 hi/lo split planes (plane offset = n elements)
__global__ void cvt_split(const float* __restrict__ src, _Float16* __restrict__ dst, int n) {
  int i = blockIdx.x * 256 + threadIdx.x;
  if (i < n) {
    float x = src[i];
    _Float16 h = (_Float16)x;
    dst[i] = h;
    dst[(size_t)n + i] = (_Float16)(x - (float)h);
  }
}

__global__ void build_wg(const float* __restrict__ W_ih, const float* __restrict__ W_hh,
                         _Float16* __restrict__ Wg) {
  int i = blockIdx.x * 256 + threadIdx.x;
  if (i < 512 * 192) {
    int r = i / 192, k = i % 192;
    float v = (k < 64) ? W_ih[r * 64 + k] : W_hh[r * 128 + (k - 64)];
    _Float16 h = (_Float16)v;
    Wg[i] = h;
    Wg[512 * 192 + i] = (_Float16)(v - (float)h);
  }
}

__global__ void build_wp1b(const float* __restrict__ Wp1, _Float16* __restrict__ W) {
  int i = blockIdx.x * 256 + threadIdx.x;
  if (i < 512 * 128) {
    int r = i >> 7, k = i & 127;
    float v = Wp1[r * 192 + 64 + k];
    _Float16 h = (_Float16)v;
    W[i] = h;
    W[512 * 128 + i] = (_Float16)(v - (float)h);
  }
}

__global__ void build_misc(const float* __restrict__ Wp1, const float* __restrict__ Wp_emb,
                           const float* __restrict__ bp_emb, const float* __restrict__ bp1,
                           const float* __restrict__ b_ih, const float* __restrict__ b_hh,
                           float* __restrict__ Uc, float* __restrict__ c1,
                           float* __restrict__ bias_g) {
  int r = blockIdx.x * 256 + threadIdx.x;
  if (r < 512) {
    float u0 = 0.f, u1 = 0.f, cc = 0.f;
    for (int e = 0; e < 64; e++) {
      float w = Wp1[r * 192 + e];
      u0 += w * Wp_emb[e * 2 + 0];
      u1 += w * Wp_emb[e * 2 + 1];
      cc += w * bp_emb[e];
    }
    Uc[r * 2 + 0] = u0;
    Uc[r * 2 + 1] = u1;
    c1[r] = bp1[r] + cc;
    bias_g[r] = b_ih[r] + b_hh[r];
  }
}

__global__ void init_state(const float* __restrict__ lp, const float* __restrict__ lpr,
                           const float* __restrict__ h0, const float* __restrict__ c0,
                           const float* __restrict__ W_emb, const float* __restrict__ b_emb,
                           _Float16* __restrict__ A_lstm, size_t PL_AL,
                           float* __restrict__ c_state, float* __restrict__ curr_pos) {
  int row = blockIdx.x;
  int t = threadIdx.x;  // 192
  float v;
  if (t < 64) {
    v = lpr[row * 2] * W_emb[t * 2] + lpr[row * 2 + 1] * W_emb[t * 2 + 1] + b_emb[t];
  } else {
    int u = t - 64;
    v = h0[(size_t)row * 128 + u];
    c_state[(size_t)row * 128 + u] = c0[(size_t)row * 128 + u];
  }
  _Float16 h = (_Float16)v;
  A_lstm[(size_t)row * 192 + t] = h;
  A_lstm[PL_AL + (size_t)row * 192 + t] = (_Float16)(v - (float)h);
  if (t < 2) curr_pos[row * 2 + t] = lp[row * 2 + t];
}

// ---------------- generic split-fp16 MFMA GEMM ----------------
// out = act(A[M,K] @ B[N,K]^T + bias), A/B stored as fp16 hi plane + lo plane.
// acc = Ah*Bh + Ah*Bl + Al*Bh  (error ~2^-22). tile 64x64, 256 threads.

__global__ __launch_bounds__(256) void gemm_f16s(
    const _Float16* __restrict__ A, size_t aPl, int lda,
    const _Float16* __restrict__ B, size_t bPl, int ldb,
    const float* __restrict__ bias,
    float* __restrict__ outF, int ldoF,
    _Float16* __restrict__ outS, size_t oPl, int ldoS,
    int K, int relu) {
  __shared__ _Float16 Ah[64][40], Al[64][40], Bh[64][40], Bl[64][40];
  const int tid = threadIdx.x;
  const int lane = tid & 63;
  const int wid = tid >> 6;
  const int wm = wid & 1, wn = wid >> 1;
  const int m0 = blockIdx.x * 64, n0 = blockIdx.y * 64;

  f32x4 acc[2][2];
#pragma unroll
  for (int a = 0; a < 2; a++)
#pragma unroll
    for (int b = 0; b < 2; b++) acc[a][b] = (f32x4){0.f, 0.f, 0.f, 0.f};

  const int srow = tid >> 2, sc = (tid & 3) * 8;
  for (int k0 = 0; k0 < K; k0 += 32) {
    const _Float16* ap = A + (size_t)(m0 + srow) * lda + k0 + sc;
    const _Float16* bp = B + (size_t)(n0 + srow) * ldb + k0 + sc;
    *(uint4*)&Ah[srow][sc] = *(const uint4*)ap;
    *(uint4*)&Al[srow][sc] = *(const uint4*)(ap + aPl);
    *(uint4*)&Bh[srow][sc] = *(const uint4*)bp;
    *(uint4*)&Bl[srow][sc] = *(const uint4*)(bp + bPl);
    __syncthreads();
    const int ar = wm * 32 + (lane & 15), br = wn * 32 + (lane & 15), kk = (lane >> 4) * 8;
    f16x8 ah0 = *(const f16x8*)&Ah[ar][kk];
    f16x8 ah1 = *(const f16x8*)&Ah[ar + 16][kk];
    f16x8 al0 = *(const f16x8*)&Al[ar][kk];
    f16x8 al1 = *(const f16x8*)&Al[ar + 16][kk];
    f16x8 bh0 = *(const f16x8*)&Bh[br][kk];
    f16x8 bh1 = *(const f16x8*)&Bh[br + 16][kk];
    f16x8 bl0 = *(const f16x8*)&Bl[br][kk];
    f16x8 bl1 = *(const f16x8*)&Bl[br + 16][kk];
    acc[0][0] = __builtin_amdgcn_mfma_f32_16x16x32_f16(ah0, bh0, acc[0][0], 0, 0, 0);
    acc[0][0] = __builtin_amdgcn_mfma_f32_16x16x32_f16(ah0, bl0, acc[0][0], 0, 0, 0);
    acc[0][0] = __builtin_amdgcn_mfma_f32_16x16x32_f16(al0, bh0, acc[0][0], 0, 0, 0);
    acc[0][1] = __builtin_amdgcn_mfma_f32_16x16x32_f16(ah0, bh1, acc[0][1], 0, 0, 0);
    acc[0][1] = __builtin_amdgcn_mfma_f32_16x16x32_f16(ah0, bl1, acc[0][1], 0, 0, 0);
    acc[0][1] = __builtin_amdgcn_mfma_f32_16x16x32_f16(al0, bh1, acc[0][1], 0, 0, 0);
    acc[1][0] = __builtin_amdgcn_mfma_f32_16x16x32_f16(ah1, bh0, acc[1][0], 0, 0, 0);
    acc[1][0] = __builtin_amdgcn_mfma_f32_16x16x32_f16(ah1, bl0, acc[1][0], 0, 0, 0);
    acc[1][0] = __builtin_amdgcn_mfma_f32_16x16x32_f16(al1, bh0, acc[1][0], 0, 0, 0);
    acc[1][1] = __builtin_amdgcn_mfma_f32_16x16x32_f16(ah1, bh1, acc[1][1], 0, 0, 0);
    acc[1][1] = __builtin_amdgcn_mfma_f32_16x16x32_f16(ah1, bl1, acc[1][1], 0, 0, 0);
    acc[1][1] = __builtin_amdgcn_mfma_f32_16x16x32_f16(al1, bh1, acc[1][1], 0, 0, 0);
    __syncthreads();
  }
#pragma unroll
  for (int mi = 0; mi < 2; mi++)
#pragma unroll
    for (int ni = 0; ni < 2; ni++)
#pragma unroll
      for (int r = 0; r < 4; r++) {
        int row = m0 + wm * 32 + mi * 16 + (lane >> 4) * 4 + r;
        int col = n0 + wn * 32 + ni * 16 + (lane & 15);
        float v = acc[mi][ni][r];
        if (bias) v += bias[col];
        if (relu) v = fmaxf(v, 0.f);
        if (outF) outF[(size_t)row * ldoF + col] = v;
        if (outS) {
          _Float16 h = (_Float16)v;
          outS[(size_t)row * ldoS + col] = h;
          outS[oPl + (size_t)row * ldoS + col] = (_Float16)(v - (float)h);
        }
      }
}

// ---------------- LSTM pointwise + pose head (all fp32) ----------------

__global__ __launch_bounds__(256) void lstm_pointwise(
    const float* __restrict__ gates, float* __restrict__ c_state,
    _Float16* __restrict__ A_mlp, size_t PL_AM,   // h_lstm -> cols 0..127 (ld 1152)
    float* __restrict__ curr_pos,
    float* __restrict__ rels_out,
    _Float16* __restrict__ A_lstm, size_t PL_AL,  // dec_in -> cols 0..63 (ld 192)
    const float* __restrict__ W_pos, const float* __restrict__ b_pos,
    const float* __restrict__ W_emb, const float* __restrict__ b_emb) {
  __shared__ float hbuf[16][128];
  __shared__ float rp[16][2];
  int tid = threadIdx.x;
  int r = tid >> 4, l16 = tid & 15;
  int row = blockIdx.x * 16 + r;
  const float* g = gates + (size_t)row * 512;
#pragma unroll
  for (int s = 0; s < 8; s++) {
    int u = l16 + s * 16;
    float gi = g[u], gf = g[128 + u], gg = g[256 + u], go = g[384 + u];
    float si = 1.f / (1.f + expf(-gi));
    float sf = 1.f / (1.f + expf(-gf));
    float so = 1.f / (1.f + expf(-go));
    float c = sf * c_state[(size_t)row * 128 + u] + si * tanhf(gg);
    c_state[(size_t)row * 128 + u] = c;
    float h = so * tanhf(c);
    hbuf[r][u] = h;
    _Float16 hh = (_Float16)h;
    A_mlp[(size_t)row * 1152 + u] = hh;
    A_mlp[PL_AM + (size_t)row * 1152 + u] = (_Float16)(h - (float)hh);
  }
  __syncthreads();
  if (tid < 32) {
    int rr = tid >> 1, o = tid & 1;
    int rowg = blockIdx.x * 16 + rr;
    float s = b_pos[o];
    const float* w = W_pos + o * 128;
    for (int k = 0; k < 128; k++) s += hbuf[rr][k] * w[k];
    rp[rr][o] = s;
    rels_out[(size_t)rowg * 2 + o] = s;
    curr_pos[(size_t)rowg * 2 + o] += s;
  }
  __syncthreads();
#pragma unroll
  for (int s = 0; s < 4; s++) {
    int u = l16 + s * 16;
    float v = rp[r][0] * W_emb[u * 2] + rp[r][1] * W_emb[u * 2 + 1] + b_emb[u];
    _Float16 hh = (_Float16)v;
    A_lstm[(size_t)row * 192 + u] = hh;
    A_lstm[PL_AL + (size_t)row * 192 + u] = (_Float16)(v - (float)hh);
  }
}

// ---------------- build x1 = relu(hpart[g,j] + rank2(i,j)) split fp16 ----------------

__global__ __launch_bounds__(256) void build_x1(
    const float* __restrict__ hpart, const float* __restrict__ curr_pos,
    const float4* __restrict__ Uc2, unsigned int* __restrict__ x1, size_t xPlU,
    int g_base) {
  int b = blockIdx.x;
  int gl = b / 24, i = b % 24;
  int g = g_base + gl;
  int t = threadIdx.x;  // 256: k pair = 2t,2t+1
  float pix = curr_pos[(g * 24 + i) * 2], piy = curr_pos[(g * 24 + i) * 2 + 1];
  float4 uc = Uc2[t];
  for (int j = 0; j < 24; j++) {
    float dx = curr_pos[(g * 24 + j) * 2] - pix;
    float dy = curr_pos[(g * 24 + j) * 2 + 1] - piy;
    float nrm = sqrtf(dx * dx + dy * dy);
    float inv = 1.f / fmaxf(nrm, 1e-12f);
    float u0 = dx * inv, u1 = dy * inv;
    float2 hp = *(const float2*)(hpart + (size_t)(g * 24 + j) * 512 + 2 * t);
    float v0 = fmaxf(hp.x + u0 * uc.x + u1 * uc.y, 0.f);
    float v1 = fmaxf(hp.y + u0 * uc.z + u1 * uc.w, 0.f);
    _Float16 h0v = (_Float16)v0, h1v = (_Float16)v1;
    _Float16 l0v = (_Float16)(v0 - (float)h0v), l1v = (_Float16)(v1 - (float)h1v);
    unsigned int ph = (unsigned int)h2u(h0v) | ((unsigned int)h2u(h1v) << 16);
    unsigned int pl = (unsigned int)h2u(l0v) | ((unsigned int)h2u(l1v) << 16);
    size_t idx = ((size_t)(gl * 576) + i * 24 + j) * 256 + t;
    x1[idx] = ph;
    x1[xPlU + idx] = pl;
  }
}

// ---------------- pool GEMM (96x256 tile, split fp16) + fused max over j ----------------

__global__ __launch_bounds__(512) void pool_gemm(
    const _Float16* __restrict__ x1, size_t xPl,   // [nGc*576, 512]
    const _Float16* __restrict__ W2, size_t wPl,   // [1024, 512]
    const float* __restrict__ bp2,
    _Float16* __restrict__ A_mlp, size_t oPl,      // out cols 128..1151 (ld 1152)
    int g_base) {
  __shared__ _Float16 Ah[96][40], Al[96][40], Bh[256][40], Bl[256][40];
  __shared__ int pool_tile[4][256];
  int b = blockIdx.x;
  int nt = b & 3;
  int it = (b >> 2) % 6;
  int gl = b / 24;
  int tid = threadIdx.x;
  int lane = tid & 63, wid = tid >> 6;
  int wm = wid & 1, wn = wid >> 1;  // wm:2, wn:4

  int* pt = &pool_tile[0][0];
  pt[tid] = 0;
  pt[tid + 512] = 0;

  f32x4 acc[3][4];
#pragma unroll
  for (int a = 0; a < 3; a++)
#pragma unroll
    for (int c = 0; c < 4; c++) acc[a][c] = (f32x4){0.f, 0.f, 0.f, 0.f};

  const int arow = tid >> 2, ac = (tid & 3) * 8;
  for (int k0 = 0; k0 < 512; k0 += 32) {
    if (tid < 384) {
      const _Float16* ap = x1 + ((size_t)(gl * 576 + it * 96 + arow)) * 512 + k0 + ac;
      *(uint4*)&Ah[arow][ac] = *(const uint4*)ap;
      *(uint4*)&Al[arow][ac] = *(const uint4*)(ap + xPl);
    }
    for (int c = tid; c < 1024; c += 512) {
      int rowb = c >> 2, cc = (c & 3) * 8;
      const _Float16* bp = W2 + ((size_t)(nt * 256 + rowb)) * 512 + k0 + cc;
      *(uint4*)&Bh[rowb][cc] = *(const uint4*)bp;
      *(uint4*)&Bl[rowb][cc] = *(const uint4*)(bp + wPl);
    }
    __syncthreads();
    const int kk = (lane >> 4) * 8;
    f16x8 ah[3], al[3], bh[4], bl[4];
#pragma unroll
    for (int mi = 0; mi < 3; mi++) {
      int ar = wm * 48 + mi * 16 + (lane & 15);
      ah[mi] = *(const f16x8*)&Ah[ar][kk];
      al[mi] = *(const f16x8*)&Al[ar][kk];
    }
#pragma unroll
    for (int ni = 0; ni < 4; ni++) {
      int br = wn * 64 + ni * 16 + (lane & 15);
      bh[ni] = *(const f16x8*)&Bh[br][kk];
      bl[ni] = *(const f16x8*)&Bl[br][kk];
    }
#pragma unroll
    for (int mi = 0; mi < 3; mi++)
#pragma unroll
      for (int ni = 0; ni < 4; ni++) {
        acc[mi][ni] = __builtin_amdgcn_mfma_f32_16x16x32_f16(ah[mi], bh[ni], acc[mi][ni], 0, 0, 0);
        acc[mi][ni] = __builtin_amdgcn_mfma_f32_16x16x32_f16(ah[mi], bl[ni], acc[mi][ni], 0, 0, 0);
        acc[mi][ni] = __builtin_amdgcn_mfma_f32_16x16x32_f16(al[mi], bh[ni], acc[mi][ni], 0, 0, 0);
      }
    __syncthreads();
  }
#pragma unroll
  for (int mi = 0; mi < 3; mi++)
#pragma unroll
    for (int ni = 0; ni < 4; ni++)
#pragma unroll
      for (int r = 0; r < 4; r++) {
        int rl = wm * 48 + mi * 16 + (lane >> 4) * 4 + r;  // 0..95
        int il = rl / 24;                                  // 0..3
        int nl = wn * 64 + ni * 16 + (lane & 15);          // 0..255
        float z = fmaxf(acc[mi][ni][r] + bp2[nt * 256 + nl], 0.f);
        atomicMax(&pool_tile[il][nl], __float_as_int(z));
      }
  __syncthreads();
  int g = g_base + gl;
  for (int idx = tid; idx < 1024; idx += 512) {
    int il = idx >> 8, nl = idx & 255;
    int row = g * 24 + it * 4 + il;
    float z = __int_as_float(pool_tile[il][nl]);
    _Float16 h = (_Float16)z;
    A_mlp[(size_t)row * 1152 + 128 + nt * 256 + nl] = h;
    A_mlp[oPl + (size_t)row * 1152 + 128 + nt * 256 + nl] = (_Float16)(z - (float)h);
  }
}

// ---------------- host ----------------

extern "C" void kernel_launch(void* const* d_in, const int* in_sizes, int n_in,
                              void* d_out, int out_size, void* d_ws, size_t ws_size,
                              hipStream_t stream) {
  (void)in_sizes; (void)n_in; (void)out_size;
  const float* last_pos     = (const float*)d_in[0];
  const float* last_pos_rel = (const float*)d_in[1];
  const float* h0    = (const float*)d_in[2];
  const float* c0    = (const float*)d_in[3];
  const float* W_emb = (const float*)d_in[5];
  const float* b_emb = (const float*)d_in[6];
  const float* W_ih  = (const float*)d_in[7];
  const float* W_hh  = (const float*)d_in[8];
  const float* b_ih  = (const float*)d_in[9];
  const float* b_hh  = (const float*)d_in[10];
  const float* W_pos = (const float*)d_in[11];
  const float* b_pos = (const float*)d_in[12];
  const float* Wp_emb = (const float*)d_in[13];
  const float* bp_emb = (const float*)d_in[14];
  const float* Wp1 = (const float*)d_in[15];
  const float* bp1 = (const float*)d_in[16];
  const float* Wp2 = (const float*)d_in[17];
  const float* bp2 = (const float*)d_in[18];
  const float* Wm1 = (const float*)d_in[19];
  const float* bm1 = (const float*)d_in[20];
  const float* Wm2 = (const float*)d_in[21];
  const float* bm2 = (const float*)d_in[22];

  const size_t PL_WG   = 512 * 192;
  const size_t PL_WP1B = 512 * 128;
  const size_t PL_WP2  = (size_t)1024 * 512;
  const size_t PL_WM1  = (size_t)1024 * 1152;
  const size_t PL_WM2  = (size_t)128 * 1024;
  const size_t PL_AL   = (size_t)1536 * 192;
  const size_t PL_AM   = (size_t)1536 * 1152;
  const size_t PL_DH   = (size_t)1536 * 1024;

  char* ws = (char*)d_ws;
  size_t off = 0;
  auto alloc = [&](size_t bytes) -> void* {
    void* p = ws + off;
    off = (off + bytes + 255) & ~(size_t)255;
    return p;
  };
  _Float16* Wg_s   = (_Float16*)alloc(PL_WG * 2 * 2);
  _Float16* Wp1b_s = (_Float16*)alloc(PL_WP1B * 2 * 2);
  _Float16* Wp2_s  = (_Float16*)alloc(PL_WP2 * 2 * 2);
  _Float16* Wm1_s  = (_Float16*)alloc(PL_WM1 * 2 * 2);
  _Float16* Wm2_s  = (_Float16*)alloc(PL_WM2 * 2 * 2);
  float* Uc     = (float*)alloc(512 * 2 * 4);
  float* c1     = (float*)alloc(512 * 4);
  float* bias_g = (float*)alloc(512 * 4);
  _Float16* A_lstm = (_Float16*)alloc(PL_AL * 2 * 2);
  float* gates   = (float*)alloc((size_t)1536 * 512 * 4);
  float* c_state = (float*)alloc((size_t)1536 * 128 * 4);
  _Float16* A_mlp = (_Float16*)alloc(PL_AM * 2 * 2);
  float* curr_pos = (float*)alloc(1536 * 2 * 4);
  float* hpart = (float*)alloc((size_t)1536 * 512 * 4);
  _Float16* dh = (_Float16*)alloc(PL_DH * 2 * 2);

  // x1 chunking: largest group-chunk that fits remaining ws (hi+lo planes)
  int nGc = 64;
  while (nGc > 1 && off + (size_t)nGc * 576 * 512 * 2 * 2 > ws_size) nGc >>= 1;
  const size_t PL_X1 = (size_t)nGc * 576 * 512;   // elements per plane
  _Float16* x1 = (_Float16*)alloc(PL_X1 * 2 * 2);

  float* rels = (float*)d_out;                      // [12,1536,2]
  float* h_out = ((float*)d_out) + 12 * 1536 * 2;   // [1536,128]

  // ---- init weights + state ----
  cvt_split<<<(524288 + 255) / 256, 256, 0, stream>>>(Wp2, Wp2_s, 524288);
  cvt_split<<<(1179648 + 255) / 256, 256, 0, stream>>>(Wm1, Wm1_s, 1179648);
  cvt_split<<<(131072 + 255) / 256, 256, 0, stream>>>(Wm2, Wm2_s, 131072);
  build_wg<<<(512 * 192 + 255) / 256, 256, 0, stream>>>(W_ih, W_hh, Wg_s);
  build_wp1b<<<(512 * 128 + 255) / 256, 256, 0, stream>>>(Wp1, Wp1b_s);
  build_misc<<<2, 256, 0, stream>>>(Wp1, Wp_emb, bp_emb, bp1, b_ih, b_hh, Uc, c1, bias_g);
  init_state<<<1536, 192, 0, stream>>>(last_pos, last_pos_rel, h0, c0, W_emb, b_emb,
                                       A_lstm, PL_AL, c_state, curr_pos);

  for (int t = 0; t < 12; t++) {
    // gates = A_lstm @ Wg^T + (b_ih+b_hh)   [K=192]
    gemm_f16s<<<dim3(24, 8), 256, 0, stream>>>(A_lstm, PL_AL, 192, Wg_s, PL_WG, 192, bias_g,
                                               gates, 512, (_Float16*)nullptr, 0, 0, 192, 0);
    // LSTM pointwise + pose head + dec_in
    lstm_pointwise<<<96, 256, 0, stream>>>(gates, c_state, A_mlp, PL_AM, curr_pos,
                                           rels + (size_t)t * 1536 * 2, A_lstm, PL_AL,
                                           W_pos, b_pos, W_emb, b_emb);
    // hpart = h_lstm @ Wp1b^T + c1   [K=128]
    gemm_f16s<<<dim3(24, 8), 256, 0, stream>>>(A_mlp, PL_AM, 1152, Wp1b_s, PL_WP1B, 128, c1,
                                               hpart, 512, (_Float16*)nullptr, 0, 0, 128, 0);
    // pool_net
    for (int cb = 0; cb < 64; cb += nGc) {
      build_x1<<<nGc * 24, 256, 0, stream>>>(hpart, curr_pos, (const float4*)Uc,
                                             (unsigned int*)x1, PL_X1 / 2, cb);
      pool_gemm<<<nGc * 24, 512, 0, stream>>>(x1, PL_X1, Wp2_s, PL_WP2, bp2, A_mlp, PL_AM, cb);
    }
    // dh = relu(A_mlp @ Wm1^T + bm1)   [K=1152]
    gemm_f16s<<<dim3(24, 16), 256, 0, stream>>>(A_mlp, PL_AM, 1152, Wm1_s, PL_WM1, 1152, bm1,
                                                (float*)nullptr, 0, dh, PL_DH, 1024, 1152, 1);
    // h = relu(dh @ Wm2^T + bm2) -> A_lstm cols 64..191 (+ f32 h out last step)  [K=1024]
    float* houtF = (t == 11) ? h_out : (float*)nullptr;
    gemm_f16s<<<dim3(24, 2), 256, 0, stream>>>(dh, PL_DH, 1024, Wm2_s, PL_WM2, 1024, bm2,
                                               houtF, 128, A_lstm + 64, PL_AL, 192, 1024, 1);
  }
}

// Round 3
// 2332.861 us; speedup vs baseline: 1.0835x; 1.0835x over previous
//
#include <hip/hip_runtime.h>
#include <hip/hip_bf16.h>

typedef __attribute__((ext_vector_type(4))) float f32x4;
typedef __attribute__((ext_vector_type(8))) _Float16 f16x8;

static __device__ __forceinline__ unsigned short h2u(_Float16 h) {
  union { _Float16 h; unsigned short u; } v; v.h = h; return v.u;
}

// ---------------- init kernels ----------------

// fp32 -> fp16 hi/lo split planes (plane offset = n elements)
__global__ void cvt_split(const float* __restrict__ src, _Float16* __restrict__ dst, int n) {
  int i = blockIdx.x * 256 + threadIdx.x;
  if (i < n) {
    float x = src[i];
    _Float16 h = (_Float16)x;
    dst[i] = h;
    dst[(size_t)n + i] = (_Float16)(x - (float)h);
  }
}

__global__ void build_wg(const float* __restrict__ W_ih, const float* __restrict__ W_hh,
                         _Float16* __restrict__ Wg) {
  int i = blockIdx.x * 256 + threadIdx.x;
  if (i < 512 * 192) {
    int r = i / 192, k = i % 192;
    float v = (k < 64) ? W_ih[r * 64 + k] : W_hh[r * 128 + (k - 64)];
    _Float16 h = (_Float16)v;
    Wg[i] = h;
    Wg[512 * 192 + i] = (_Float16)(v - (float)h);
  }
}

__global__ void build_wp1b(const float* __restrict__ Wp1, _Float16* __restrict__ W) {
  int i = blockIdx.x * 256 + threadIdx.x;
  if (i < 512 * 128) {
    int r = i >> 7, k = i & 127;
    float v = Wp1[r * 192 + 64 + k];
    _Float16 h = (_Float16)v;
    W[i] = h;
    W[512 * 128 + i] = (_Float16)(v - (float)h);
  }
}

__global__ void build_misc(const float* __restrict__ Wp1, const float* __restrict__ Wp_emb,
                           const float* __restrict__ bp_emb, const float* __restrict__ bp1,
                           const float* __restrict__ b_ih, const float* __restrict__ b_hh,
                           float* __restrict__ Uc, float* __restrict__ c1,
                           float* __restrict__ bias_g) {
  int r = blockIdx.x * 256 + threadIdx.x;
  if (r < 512) {
    float u0 = 0.f, u1 = 0.f, cc = 0.f;
    for (int e = 0; e < 64; e++) {
      float w = Wp1[r * 192 + e];
      u0 += w * Wp_emb[e * 2 + 0];
      u1 += w * Wp_emb[e * 2 + 1];
      cc += w * bp_emb[e];
    }
    Uc[r * 2 + 0] = u0;
    Uc[r * 2 + 1] = u1;
    c1[r] = bp1[r] + cc;
    bias_g[r] = b_ih[r] + b_hh[r];
  }
}

__global__ void init_state(const float* __restrict__ lp, const float* __restrict__ lpr,
                           const float* __restrict__ h0, const float* __restrict__ c0,
                           const float* __restrict__ W_emb, const float* __restrict__ b_emb,
                           _Float16* __restrict__ A_lstm, size_t PL_AL,
                           float* __restrict__ c_state, float* __restrict__ curr_pos) {
  int row = blockIdx.x;
  int t = threadIdx.x;  // 192
  float v;
  if (t < 64) {
    v = lpr[row * 2] * W_emb[t * 2] + lpr[row * 2 + 1] * W_emb[t * 2 + 1] + b_emb[t];
  } else {
    int u = t - 64;
    v = h0[(size_t)row * 128 + u];
    c_state[(size_t)row * 128 + u] = c0[(size_t)row * 128 + u];
  }
  _Float16 h = (_Float16)v;
  A_lstm[(size_t)row * 192 + t] = h;
  A_lstm[PL_AL + (size_t)row * 192 + t] = (_Float16)(v - (float)h);
  if (t < 2) curr_pos[row * 2 + t] = lp[row * 2 + t];
}

// ---------------- generic split-fp16 MFMA GEMM ----------------
// out = act(A[M,K] @ B[N,K]^T + bias), A/B stored as fp16 hi plane + lo plane.
// acc = Ah*Bh + Ah*Bl + Al*Bh  (error ~2^-22). tile 64x64, 256 threads.

__global__ __launch_bounds__(256) void gemm_f16s(
    const _Float16* __restrict__ A, size_t aPl, int lda,
    const _Float16* __restrict__ B, size_t bPl, int ldb,
    const float* __restrict__ bias,
    float* __restrict__ outF, int ldoF,
    _Float16* __restrict__ outS, size_t oPl, int ldoS,
    int K, int relu) {
  __shared__ _Float16 Ah[64][40], Al[64][40], Bh[64][40], Bl[64][40];
  const int tid = threadIdx.x;
  const int lane = tid & 63;
  const int wid = tid >> 6;
  const int wm = wid & 1, wn = wid >> 1;
  const int m0 = blockIdx.x * 64, n0 = blockIdx.y * 64;

  f32x4 acc[2][2];
#pragma unroll
  for (int a = 0; a < 2; a++)
#pragma unroll
    for (int b = 0; b < 2; b++) acc[a][b] = (f32x4){0.f, 0.f, 0.f, 0.f};

  const int srow = tid >> 2, sc = (tid & 3) * 8;
  for (int k0 = 0; k0 < K; k0 += 32) {
    const _Float16* ap = A + (size_t)(m0 + srow) * lda + k0 + sc;
    const _Float16* bp = B + (size_t)(n0 + srow) * ldb + k0 + sc;
    *(uint4*)&Ah[srow][sc] = *(const uint4*)ap;
    *(uint4*)&Al[srow][sc] = *(const uint4*)(ap + aPl);
    *(uint4*)&Bh[srow][sc] = *(const uint4*)bp;
    *(uint4*)&Bl[srow][sc] = *(const uint4*)(bp + bPl);
    __syncthreads();
    const int ar = wm * 32 + (lane & 15), br = wn * 32 + (lane & 15), kk = (lane >> 4) * 8;
    f16x8 ah0 = *(const f16x8*)&Ah[ar][kk];
    f16x8 ah1 = *(const f16x8*)&Ah[ar + 16][kk];
    f16x8 al0 = *(const f16x8*)&Al[ar][kk];
    f16x8 al1 = *(const f16x8*)&Al[ar + 16][kk];
    f16x8 bh0 = *(const f16x8*)&Bh[br][kk];
    f16x8 bh1 = *(const f16x8*)&Bh[br + 16][kk];
    f16x8 bl0 = *(const f16x8*)&Bl[br][kk];
    f16x8 bl1 = *(const f16x8*)&Bl[br + 16][kk];
    acc[0][0] = __builtin_amdgcn_mfma_f32_16x16x32_f16(ah0, bh0, acc[0][0], 0, 0, 0);
    acc[0][0] = __builtin_amdgcn_mfma_f32_16x16x32_f16(ah0, bl0, acc[0][0], 0, 0, 0);
    acc[0][0] = __builtin_amdgcn_mfma_f32_16x16x32_f16(al0, bh0, acc[0][0], 0, 0, 0);
    acc[0][1] = __builtin_amdgcn_mfma_f32_16x16x32_f16(ah0, bh1, acc[0][1], 0, 0, 0);
    acc[0][1] = __builtin_amdgcn_mfma_f32_16x16x32_f16(ah0, bl1, acc[0][1], 0, 0, 0);
    acc[0][1] = __builtin_amdgcn_mfma_f32_16x16x32_f16(al0, bh1, acc[0][1], 0, 0, 0);
    acc[1][0] = __builtin_amdgcn_mfma_f32_16x16x32_f16(ah1, bh0, acc[1][0], 0, 0, 0);
    acc[1][0] = __builtin_amdgcn_mfma_f32_16x16x32_f16(ah1, bl0, acc[1][0], 0, 0, 0);
    acc[1][0] = __builtin_amdgcn_mfma_f32_16x16x32_f16(al1, bh0, acc[1][0], 0, 0, 0);
    acc[1][1] = __builtin_amdgcn_mfma_f32_16x16x32_f16(ah1, bh1, acc[1][1], 0, 0, 0);
    acc[1][1] = __builtin_amdgcn_mfma_f32_16x16x32_f16(ah1, bl1, acc[1][1], 0, 0, 0);
    acc[1][1] = __builtin_amdgcn_mfma_f32_16x16x32_f16(al1, bh1, acc[1][1], 0, 0, 0);
    __syncthreads();
  }
#pragma unroll
  for (int mi = 0; mi < 2; mi++)
#pragma unroll
    for (int ni = 0; ni < 2; ni++)
#pragma unroll
      for (int r = 0; r < 4; r++) {
        int row = m0 + wm * 32 + mi * 16 + (lane >> 4) * 4 + r;
        int col = n0 + wn * 32 + ni * 16 + (lane & 15);
        float v = acc[mi][ni][r];
        if (bias) v += bias[col];
        if (relu) v = fmaxf(v, 0.f);
        if (outF) outF[(size_t)row * ldoF + col] = v;
        if (outS) {
          _Float16 h = (_Float16)v;
          outS[(size_t)row * ldoS + col] = h;
          outS[oPl + (size_t)row * ldoS + col] = (_Float16)(v - (float)h);
        }
      }
}

// ---------------- LSTM pointwise + pose head (all fp32) ----------------

__global__ __launch_bounds__(256) void lstm_pointwise(
    const float* __restrict__ gates, float* __restrict__ c_state,
    _Float16* __restrict__ A_mlp, size_t PL_AM,   // h_lstm -> cols 0..127 (ld 1152)
    float* __restrict__ curr_pos,
    float* __restrict__ rels_out,
    _Float16* __restrict__ A_lstm, size_t PL_AL,  // dec_in -> cols 0..63 (ld 192)
    const float* __restrict__ W_pos, const float* __restrict__ b_pos,
    const float* __restrict__ W_emb, const float* __restrict__ b_emb) {
  __shared__ float hbuf[16][128];
  __shared__ float rp[16][2];
  int tid = threadIdx.x;
  int r = tid >> 4, l16 = tid & 15;
  int row = blockIdx.x * 16 + r;
  const float* g = gates + (size_t)row * 512;
#pragma unroll
  for (int s = 0; s < 8; s++) {
    int u = l16 + s * 16;
    float gi = g[u], gf = g[128 + u], gg = g[256 + u], go = g[384 + u];
    float si = 1.f / (1.f + expf(-gi));
    float sf = 1.f / (1.f + expf(-gf));
    float so = 1.f / (1.f + expf(-go));
    float c = sf * c_state[(size_t)row * 128 + u] + si * tanhf(gg);
    c_state[(size_t)row * 128 + u] = c;
    float h = so * tanhf(c);
    hbuf[r][u] = h;
    _Float16 hh = (_Float16)h;
    A_mlp[(size_t)row * 1152 + u] = hh;
    A_mlp[PL_AM + (size_t)row * 1152 + u] = (_Float16)(h - (float)hh);
  }
  __syncthreads();
  if (tid < 32) {
    int rr = tid >> 1, o = tid & 1;
    int rowg = blockIdx.x * 16 + rr;
    float s = b_pos[o];
    const float* w = W_pos + o * 128;
    for (int k = 0; k < 128; k++) s += hbuf[rr][k] * w[k];
    rp[rr][o] = s;
    rels_out[(size_t)rowg * 2 + o] = s;
    curr_pos[(size_t)rowg * 2 + o] += s;
  }
  __syncthreads();
#pragma unroll
  for (int s = 0; s < 4; s++) {
    int u = l16 + s * 16;
    float v = rp[r][0] * W_emb[u * 2] + rp[r][1] * W_emb[u * 2 + 1] + b_emb[u];
    _Float16 hh = (_Float16)v;
    A_lstm[(size_t)row * 192 + u] = hh;
    A_lstm[PL_AL + (size_t)row * 192 + u] = (_Float16)(v - (float)hh);
  }
}

// ---------------- fused pool: build x1 tile in-LDS + GEMM + max over j ----------------
// A row (of 576 per group) = i*24 + j; x1[row,k] = relu(hpart[g*24+j,k] + u0*Uc[k,0] + u1*Uc[k,1])
// grid: 64 groups x 6 it x 4 nt = 1536 blocks; tile 96 rows x 256 cols, K=512.

__global__ __launch_bounds__(512) void pool_gemm(
    const float* __restrict__ hpart,     // [1536,512] f32
    const float* __restrict__ curr_pos,  // [1536,2] f32
    const float* __restrict__ Uc,        // [512,2] f32
    const _Float16* __restrict__ W2, size_t wPl,   // [1024, 512] hi/lo
    const float* __restrict__ bp2,
    _Float16* __restrict__ A_mlp, size_t oPl) {    // out cols 128..1151 (ld 1152)
  __shared__ _Float16 Ah[96][40], Al[96][40], Bh[256][40], Bl[256][40];
  __shared__ float Us0[96], Us1[96];
  __shared__ int pool_tile[4][256];
  int b = blockIdx.x;
  int nt = b & 3;
  int it = (b >> 2) % 6;
  int g = b / 24;
  int tid = threadIdx.x;
  int lane = tid & 63, wid = tid >> 6;
  int wm = wid & 1, wn = wid >> 1;  // wm:2, wn:4

  int* pt = &pool_tile[0][0];
  pt[tid] = 0;
  pt[tid + 512] = 0;

  // unit vectors for the 96 rows of this tile
  if (tid < 96) {
    int r = tid;
    int i = it * 4 + r / 24;
    int j = r % 24;
    float pix = curr_pos[(g * 24 + i) * 2 + 0];
    float piy = curr_pos[(g * 24 + i) * 2 + 1];
    float dx = curr_pos[(g * 24 + j) * 2 + 0] - pix;
    float dy = curr_pos[(g * 24 + j) * 2 + 1] - piy;
    float nrm = sqrtf(dx * dx + dy * dy);
    float inv = 1.f / fmaxf(nrm, 1e-12f);
    Us0[r] = dx * inv;
    Us1[r] = dy * inv;
  }
  __syncthreads();

  f32x4 acc[3][4];
#pragma unroll
  for (int a = 0; a < 3; a++)
#pragma unroll
    for (int c = 0; c < 4; c++) acc[a][c] = (f32x4){0.f, 0.f, 0.f, 0.f};

  for (int k0 = 0; k0 < 512; k0 += 32) {
    // stage B slice [256][32] hi+lo
    for (int c = tid; c < 1024; c += 512) {
      int rowb = c >> 2, cc = (c & 3) * 8;
      const _Float16* bp = W2 + ((size_t)(nt * 256 + rowb)) * 512 + k0 + cc;
      *(uint4*)&Bh[rowb][cc] = *(const uint4*)bp;
      *(uint4*)&Bl[rowb][cc] = *(const uint4*)(bp + wPl);
    }
    // build A tile [96][32] on the fly (2 elements per thread per s-iter)
#pragma unroll
    for (int s = 0; s < 3; s++) {
      int eidx = (s * 512 + tid) * 2;  // 0..3070, even
      int r = eidx >> 5;
      int kc = eidx & 31;
      int j = r % 24;
      float2 hp = *(const float2*)(hpart + ((size_t)(g * 24 + j)) * 512 + k0 + kc);
      float4 uc = *(const float4*)(Uc + (size_t)(k0 + kc) * 2);
      float u0 = Us0[r], u1 = Us1[r];
      float v0 = fmaxf(hp.x + u0 * uc.x + u1 * uc.y, 0.f);
      float v1 = fmaxf(hp.y + u0 * uc.z + u1 * uc.w, 0.f);
      _Float16 h0v = (_Float16)v0, h1v = (_Float16)v1;
      _Float16 l0v = (_Float16)(v0 - (float)h0v), l1v = (_Float16)(v1 - (float)h1v);
      *(unsigned int*)&Ah[r][kc] = (unsigned int)h2u(h0v) | ((unsigned int)h2u(h1v) << 16);
      *(unsigned int*)&Al[r][kc] = (unsigned int)h2u(l0v) | ((unsigned int)h2u(l1v) << 16);
    }
    __syncthreads();
    const int kk = (lane >> 4) * 8;
    f16x8 ah[3], al[3], bh[4], bl[4];
#pragma unroll
    for (int mi = 0; mi < 3; mi++) {
      int ar = wm * 48 + mi * 16 + (lane & 15);
      ah[mi] = *(const f16x8*)&Ah[ar][kk];
      al[mi] = *(const f16x8*)&Al[ar][kk];
    }
#pragma unroll
    for (int ni = 0; ni < 4; ni++) {
      int br = wn * 64 + ni * 16 + (lane & 15);
      bh[ni] = *(const f16x8*)&Bh[br][kk];
      bl[ni] = *(const f16x8*)&Bl[br][kk];
    }
#pragma unroll
    for (int mi = 0; mi < 3; mi++)
#pragma unroll
      for (int ni = 0; ni < 4; ni++) {
        acc[mi][ni] = __builtin_amdgcn_mfma_f32_16x16x32_f16(ah[mi], bh[ni], acc[mi][ni], 0, 0, 0);
        acc[mi][ni] = __builtin_amdgcn_mfma_f32_16x16x32_f16(ah[mi], bl[ni], acc[mi][ni], 0, 0, 0);
        acc[mi][ni] = __builtin_amdgcn_mfma_f32_16x16x32_f16(al[mi], bh[ni], acc[mi][ni], 0, 0, 0);
      }
    __syncthreads();
  }
#pragma unroll
  for (int mi = 0; mi < 3; mi++)
#pragma unroll
    for (int ni = 0; ni < 4; ni++)
#pragma unroll
      for (int r = 0; r < 4; r++) {
        int rl = wm * 48 + mi * 16 + (lane >> 4) * 4 + r;  // 0..95
        int il = rl / 24;                                  // 0..3
        int nl = wn * 64 + ni * 16 + (lane & 15);          // 0..255
        float z = fmaxf(acc[mi][ni][r] + bp2[nt * 256 + nl], 0.f);
        atomicMax(&pool_tile[il][nl], __float_as_int(z));
      }
  __syncthreads();
  for (int idx = tid; idx < 1024; idx += 512) {
    int il = idx >> 8, nl = idx & 255;
    int row = g * 24 + it * 4 + il;
    float z = __int_as_float(pool_tile[il][nl]);
    _Float16 h = (_Float16)z;
    A_mlp[(size_t)row * 1152 + 128 + nt * 256 + nl] = h;
    A_mlp[oPl + (size_t)row * 1152 + 128 + nt * 256 + nl] = (_Float16)(z - (float)h);
  }
}

// ---------------- host ----------------

extern "C" void kernel_launch(void* const* d_in, const int* in_sizes, int n_in,
                              void* d_out, int out_size, void* d_ws, size_t ws_size,
                              hipStream_t stream) {
  (void)in_sizes; (void)n_in; (void)out_size; (void)ws_size;
  const float* last_pos     = (const float*)d_in[0];
  const float* last_pos_rel = (const float*)d_in[1];
  const float* h0    = (const float*)d_in[2];
  const float* c0    = (const float*)d_in[3];
  const float* W_emb = (const float*)d_in[5];
  const float* b_emb = (const float*)d_in[6];
  const float* W_ih  = (const float*)d_in[7];
  const float* W_hh  = (const float*)d_in[8];
  const float* b_ih  = (const float*)d_in[9];
  const float* b_hh  = (const float*)d_in[10];
  const float* W_pos = (const float*)d_in[11];
  const float* b_pos = (const float*)d_in[12];
  const float* Wp_emb = (const float*)d_in[13];
  const float* bp_emb = (const float*)d_in[14];
  const float* Wp1 = (const float*)d_in[15];
  const float* bp1 = (const float*)d_in[16];
  const float* Wp2 = (const float*)d_in[17];
  const float* bp2 = (const float*)d_in[18];
  const float* Wm1 = (const float*)d_in[19];
  const float* bm1 = (const float*)d_in[20];
  const float* Wm2 = (const float*)d_in[21];
  const float* bm2 = (const float*)d_in[22];

  const size_t PL_WG   = 512 * 192;
  const size_t PL_WP1B = 512 * 128;
  const size_t PL_WP2  = (size_t)1024 * 512;
  const size_t PL_WM1  = (size_t)1024 * 1152;
  const size_t PL_WM2  = (size_t)128 * 1024;
  const size_t PL_AL   = (size_t)1536 * 192;
  const size_t PL_AM   = (size_t)1536 * 1152;
  const size_t PL_DH   = (size_t)1536 * 1024;

  char* ws = (char*)d_ws;
  size_t off = 0;
  auto alloc = [&](size_t bytes) -> void* {
    void* p = ws + off;
    off = (off + bytes + 255) & ~(size_t)255;
    return p;
  };
  _Float16* Wg_s   = (_Float16*)alloc(PL_WG * 2 * 2);
  _Float16* Wp1b_s = (_Float16*)alloc(PL_WP1B * 2 * 2);
  _Float16* Wp2_s  = (_Float16*)alloc(PL_WP2 * 2 * 2);
  _Float16* Wm1_s  = (_Float16*)alloc(PL_WM1 * 2 * 2);
  _Float16* Wm2_s  = (_Float16*)alloc(PL_WM2 * 2 * 2);
  float* Uc     = (float*)alloc(512 * 2 * 4);
  float* c1     = (float*)alloc(512 * 4);
  float* bias_g = (float*)alloc(512 * 4);
  _Float16* A_lstm = (_Float16*)alloc(PL_AL * 2 * 2);
  float* gates   = (float*)alloc((size_t)1536 * 512 * 4);
  float* c_state = (float*)alloc((size_t)1536 * 128 * 4);
  _Float16* A_mlp = (_Float16*)alloc(PL_AM * 2 * 2);
  float* curr_pos = (float*)alloc(1536 * 2 * 4);
  float* hpart = (float*)alloc((size_t)1536 * 512 * 4);
  _Float16* dh = (_Float16*)alloc(PL_DH * 2 * 2);

  float* rels = (float*)d_out;                      // [12,1536,2]
  float* h_out = ((float*)d_out) + 12 * 1536 * 2;   // [1536,128]

  // ---- init weights + state ----
  cvt_split<<<(524288 + 255) / 256, 256, 0, stream>>>(Wp2, Wp2_s, 524288);
  cvt_split<<<(1179648 + 255) / 256, 256, 0, stream>>>(Wm1, Wm1_s, 1179648);
  cvt_split<<<(131072 + 255) / 256, 256, 0, stream>>>(Wm2, Wm2_s, 131072);
  build_wg<<<(512 * 192 + 255) / 256, 256, 0, stream>>>(W_ih, W_hh, Wg_s);
  build_wp1b<<<(512 * 128 + 255) / 256, 256, 0, stream>>>(Wp1, Wp1b_s);
  build_misc<<<2, 256, 0, stream>>>(Wp1, Wp_emb, bp_emb, bp1, b_ih, b_hh, Uc, c1, bias_g);
  init_state<<<1536, 192, 0, stream>>>(last_pos, last_pos_rel, h0, c0, W_emb, b_emb,
                                       A_lstm, PL_AL, c_state, curr_pos);

  for (int t = 0; t < 12; t++) {
    // gates = A_lstm @ Wg^T + (b_ih+b_hh)   [K=192]
    gemm_f16s<<<dim3(24, 8), 256, 0, stream>>>(A_lstm, PL_AL, 192, Wg_s, PL_WG, 192, bias_g,
                                               gates, 512, (_Float16*)nullptr, 0, 0, 192, 0);
    // LSTM pointwise + pose head + dec_in
    lstm_pointwise<<<96, 256, 0, stream>>>(gates, c_state, A_mlp, PL_AM, curr_pos,
                                           rels + (size_t)t * 1536 * 2, A_lstm, PL_AL,
                                           W_pos, b_pos, W_emb, b_emb);
    // hpart = h_lstm @ Wp1b^T + c1   [K=128]
    gemm_f16s<<<dim3(24, 8), 256, 0, stream>>>(A_mlp, PL_AM, 1152, Wp1b_s, PL_WP1B, 128, c1,
                                               hpart, 512, (_Float16*)nullptr, 0, 0, 128, 0);
    // fused pool_net (build x1 in-LDS + GEMM + max)
    pool_gemm<<<1536, 512, 0, stream>>>(hpart, curr_pos, Uc, Wp2_s, PL_WP2, bp2, A_mlp, PL_AM);
    // dh = relu(A_mlp @ Wm1^T + bm1)   [K=1152]
    gemm_f16s<<<dim3(24, 16), 256, 0, stream>>>(A_mlp, PL_AM, 1152, Wm1_s, PL_WM1, 1152, bm1,
                                                (float*)nullptr, 0, dh, PL_DH, 1024, 1152, 1);
    // h = relu(dh @ Wm2^T + bm2) -> A_lstm cols 64..191 (+ f32 h out last step)  [K=1024]
    float* houtF = (t == 11) ? h_out : (float*)nullptr;
    gemm_f16s<<<dim3(24, 2), 256, 0, stream>>>(dh, PL_DH, 1024, Wm2_s, PL_WM2, 1024, bm2,
                                               houtF, 128, A_lstm + 64, PL_AL, 192, 1024, 1);
  }
}

// Round 4
// 2129.178 us; speedup vs baseline: 1.1872x; 1.0957x over previous
//
#include <hip/hip_runtime.h>
#include <hip/hip_bf16.h>

typedef __attribute__((ext_vector_type(4))) float f32x4;
typedef __attribute__((ext_vector_type(8))) _Float16 f16x8;

static __device__ __forceinline__ unsigned short h2u(_Float16 h) {
  union { _Float16 h; unsigned short u; } v; v.h = h; return v.u;
}

// ---------------- init kernels ----------------

// fp32 -> fp16 hi/lo split planes (plane offset = n elements)
__global__ void cvt_split(const float* __restrict__ src, _Float16* __restrict__ dst, int n) {
  int i = blockIdx.x * 256 + threadIdx.x;
  if (i < n) {
    float x = src[i];
    _Float16 h = (_Float16)x;
    dst[i] = h;
    dst[(size_t)n + i] = (_Float16)(x - (float)h);
  }
}

__global__ void build_wg(const float* __restrict__ W_ih, const float* __restrict__ W_hh,
                         _Float16* __restrict__ Wg) {
  int i = blockIdx.x * 256 + threadIdx.x;
  if (i < 512 * 192) {
    int r = i / 192, k = i % 192;
    float v = (k < 64) ? W_ih[r * 64 + k] : W_hh[r * 128 + (k - 64)];
    _Float16 h = (_Float16)v;
    Wg[i] = h;
    Wg[512 * 192 + i] = (_Float16)(v - (float)h);
  }
}

__global__ void build_wp1b(const float* __restrict__ Wp1, _Float16* __restrict__ W) {
  int i = blockIdx.x * 256 + threadIdx.x;
  if (i < 512 * 128) {
    int r = i >> 7, k = i & 127;
    float v = Wp1[r * 192 + 64 + k];
    _Float16 h = (_Float16)v;
    W[i] = h;
    W[512 * 128 + i] = (_Float16)(v - (float)h);
  }
}

// Wp2 [1024,512] f32 -> fragment-ordered split-f16 planes:
// frag id: (T, c, p): T = n-tile (n = T*16 + (l&15)), c = K-step (k = c*32 + (l>>4)*8 + e), p = hi/lo
// W2f[(((T*16 + c)*2 + p)*64 + l)*8 + e]
__global__ void build_w2f(const float* __restrict__ Wp2, _Float16* __restrict__ W2f) {
  int idx = blockIdx.x * 256 + threadIdx.x;  // 64*16*64 = 65536 threads
  if (idx >= 65536) return;
  int l = idx & 63;
  int c = (idx >> 6) & 15;
  int T = idx >> 10;
  int n = T * 16 + (l & 15);
  int kbase = c * 32 + (l >> 4) * 8;
  size_t dst = ((size_t)((T * 16 + c) * 2) * 64 + l) * 8;
  for (int e = 0; e < 8; e++) {
    float v = Wp2[(size_t)n * 512 + kbase + e];
    _Float16 h = (_Float16)v;
    W2f[dst + e] = h;
    W2f[dst + 512 + e] = (_Float16)(v - (float)h);  // lo plane frag is +512 halves
  }
}

__global__ void build_misc(const float* __restrict__ Wp1, const float* __restrict__ Wp_emb,
                           const float* __restrict__ bp_emb, const float* __restrict__ bp1,
                           const float* __restrict__ b_ih, const float* __restrict__ b_hh,
                           float* __restrict__ Uc, float* __restrict__ c1,
                           float* __restrict__ bias_g) {
  int r = blockIdx.x * 256 + threadIdx.x;
  if (r < 512) {
    float u0 = 0.f, u1 = 0.f, cc = 0.f;
    for (int e = 0; e < 64; e++) {
      float w = Wp1[r * 192 + e];
      u0 += w * Wp_emb[e * 2 + 0];
      u1 += w * Wp_emb[e * 2 + 1];
      cc += w * bp_emb[e];
    }
    Uc[r * 2 + 0] = u0;
    Uc[r * 2 + 1] = u1;
    c1[r] = bp1[r] + cc;
    bias_g[r] = b_ih[r] + b_hh[r];
  }
}

__global__ void init_state(const float* __restrict__ lp, const float* __restrict__ lpr,
                           const float* __restrict__ h0, const float* __restrict__ c0,
                           const float* __restrict__ W_emb, const float* __restrict__ b_emb,
                           _Float16* __restrict__ A_lstm, size_t PL_AL,
                           float* __restrict__ c_state, float* __restrict__ curr_pos) {
  int row = blockIdx.x;
  int t = threadIdx.x;  // 192
  float v;
  if (t < 64) {
    v = lpr[row * 2] * W_emb[t * 2] + lpr[row * 2 + 1] * W_emb[t * 2 + 1] + b_emb[t];
  } else {
    int u = t - 64;
    v = h0[(size_t)row * 128 + u];
    c_state[(size_t)row * 128 + u] = c0[(size_t)row * 128 + u];
  }
  _Float16 h = (_Float16)v;
  A_lstm[(size_t)row * 192 + t] = h;
  A_lstm[PL_AL + (size_t)row * 192 + t] = (_Float16)(v - (float)h);
  if (t < 2) curr_pos[row * 2 + t] = lp[row * 2 + t];
}

// ---------------- generic split-fp16 MFMA GEMM ----------------

__global__ __launch_bounds__(256) void gemm_f16s(
    const _Float16* __restrict__ A, size_t aPl, int lda,
    const _Float16* __restrict__ B, size_t bPl, int ldb,
    const float* __restrict__ bias,
    float* __restrict__ outF, int ldoF,
    _Float16* __restrict__ outS, size_t oPl, int ldoS,
    int K, int relu) {
  __shared__ _Float16 Ah[64][40], Al[64][40], Bh[64][40], Bl[64][40];
  const int tid = threadIdx.x;
  const int lane = tid & 63;
  const int wid = tid >> 6;
  const int wm = wid & 1, wn = wid >> 1;
  const int m0 = blockIdx.x * 64, n0 = blockIdx.y * 64;

  f32x4 acc[2][2];
#pragma unroll
  for (int a = 0; a < 2; a++)
#pragma unroll
    for (int b = 0; b < 2; b++) acc[a][b] = (f32x4){0.f, 0.f, 0.f, 0.f};

  const int srow = tid >> 2, sc = (tid & 3) * 8;
  for (int k0 = 0; k0 < K; k0 += 32) {
    const _Float16* ap = A + (size_t)(m0 + srow) * lda + k0 + sc;
    const _Float16* bp = B + (size_t)(n0 + srow) * ldb + k0 + sc;
    *(uint4*)&Ah[srow][sc] = *(const uint4*)ap;
    *(uint4*)&Al[srow][sc] = *(const uint4*)(ap + aPl);
    *(uint4*)&Bh[srow][sc] = *(const uint4*)bp;
    *(uint4*)&Bl[srow][sc] = *(const uint4*)(bp + bPl);
    __syncthreads();
    const int ar = wm * 32 + (lane & 15), br = wn * 32 + (lane & 15), kk = (lane >> 4) * 8;
    f16x8 ah0 = *(const f16x8*)&Ah[ar][kk];
    f16x8 ah1 = *(const f16x8*)&Ah[ar + 16][kk];
    f16x8 al0 = *(const f16x8*)&Al[ar][kk];
    f16x8 al1 = *(const f16x8*)&Al[ar + 16][kk];
    f16x8 bh0 = *(const f16x8*)&Bh[br][kk];
    f16x8 bh1 = *(const f16x8*)&Bh[br + 16][kk];
    f16x8 bl0 = *(const f16x8*)&Bl[br][kk];
    f16x8 bl1 = *(const f16x8*)&Bl[br + 16][kk];
    acc[0][0] = __builtin_amdgcn_mfma_f32_16x16x32_f16(ah0, bh0, acc[0][0], 0, 0, 0);
    acc[0][0] = __builtin_amdgcn_mfma_f32_16x16x32_f16(ah0, bl0, acc[0][0], 0, 0, 0);
    acc[0][0] = __builtin_amdgcn_mfma_f32_16x16x32_f16(al0, bh0, acc[0][0], 0, 0, 0);
    acc[0][1] = __builtin_amdgcn_mfma_f32_16x16x32_f16(ah0, bh1, acc[0][1], 0, 0, 0);
    acc[0][1] = __builtin_amdgcn_mfma_f32_16x16x32_f16(ah0, bl1, acc[0][1], 0, 0, 0);
    acc[0][1] = __builtin_amdgcn_mfma_f32_16x16x32_f16(al0, bh1, acc[0][1], 0, 0, 0);
    acc[1][0] = __builtin_amdgcn_mfma_f32_16x16x32_f16(ah1, bh0, acc[1][0], 0, 0, 0);
    acc[1][0] = __builtin_amdgcn_mfma_f32_16x16x32_f16(ah1, bl0, acc[1][0], 0, 0, 0);
    acc[1][0] = __builtin_amdgcn_mfma_f32_16x16x32_f16(al1, bh0, acc[1][0], 0, 0, 0);
    acc[1][1] = __builtin_amdgcn_mfma_f32_16x16x32_f16(ah1, bh1, acc[1][1], 0, 0, 0);
    acc[1][1] = __builtin_amdgcn_mfma_f32_16x16x32_f16(ah1, bl1, acc[1][1], 0, 0, 0);
    acc[1][1] = __builtin_amdgcn_mfma_f32_16x16x32_f16(al1, bh1, acc[1][1], 0, 0, 0);
    __syncthreads();
  }
#pragma unroll
  for (int mi = 0; mi < 2; mi++)
#pragma unroll
    for (int ni = 0; ni < 2; ni++)
#pragma unroll
      for (int r = 0; r < 4; r++) {
        int row = m0 + wm * 32 + mi * 16 + (lane >> 4) * 4 + r;
        int col = n0 + wn * 32 + ni * 16 + (lane & 15);
        float v = acc[mi][ni][r];
        if (bias) v += bias[col];
        if (relu) v = fmaxf(v, 0.f);
        if (outF) outF[(size_t)row * ldoF + col] = v;
        if (outS) {
          _Float16 h = (_Float16)v;
          outS[(size_t)row * ldoS + col] = h;
          outS[oPl + (size_t)row * ldoS + col] = (_Float16)(v - (float)h);
        }
      }
}

// ---------------- LSTM pointwise + pose head (all fp32) ----------------

__global__ __launch_bounds__(256) void lstm_pointwise(
    const float* __restrict__ gates, float* __restrict__ c_state,
    _Float16* __restrict__ A_mlp, size_t PL_AM,
    float* __restrict__ curr_pos,
    float* __restrict__ rels_out,
    _Float16* __restrict__ A_lstm, size_t PL_AL,
    const float* __restrict__ W_pos, const float* __restrict__ b_pos,
    const float* __restrict__ W_emb, const float* __restrict__ b_emb) {
  __shared__ float hbuf[16][128];
  __shared__ float rp[16][2];
  int tid = threadIdx.x;
  int r = tid >> 4, l16 = tid & 15;
  int row = blockIdx.x * 16 + r;
  const float* g = gates + (size_t)row * 512;
#pragma unroll
  for (int s = 0; s < 8; s++) {
    int u = l16 + s * 16;
    float gi = g[u], gf = g[128 + u], gg = g[256 + u], go = g[384 + u];
    float si = 1.f / (1.f + expf(-gi));
    float sf = 1.f / (1.f + expf(-gf));
    float so = 1.f / (1.f + expf(-go));
    float c = sf * c_state[(size_t)row * 128 + u] + si * tanhf(gg);
    c_state[(size_t)row * 128 + u] = c;
    float h = so * tanhf(c);
    hbuf[r][u] = h;
    _Float16 hh = (_Float16)h;
    A_mlp[(size_t)row * 1152 + u] = hh;
    A_mlp[PL_AM + (size_t)row * 1152 + u] = (_Float16)(h - (float)hh);
  }
  __syncthreads();
  if (tid < 32) {
    int rr = tid >> 1, o = tid & 1;
    int rowg = blockIdx.x * 16 + rr;
    float s = b_pos[o];
    const float* w = W_pos + o * 128;
    for (int k = 0; k < 128; k++) s += hbuf[rr][k] * w[k];
    rp[rr][o] = s;
    rels_out[(size_t)rowg * 2 + o] = s;
    curr_pos[(size_t)rowg * 2 + o] += s;
  }
  __syncthreads();
#pragma unroll
  for (int s = 0; s < 4; s++) {
    int u = l16 + s * 16;
    float v = rp[r][0] * W_emb[u * 2] + rp[r][1] * W_emb[u * 2 + 1] + b_emb[u];
    _Float16 hh = (_Float16)v;
    A_lstm[(size_t)row * 192 + u] = hh;
    A_lstm[PL_AL + (size_t)row * 192 + u] = (_Float16)(v - (float)hh);
  }
}

// ---------------- fused pool: A built in-LDS, B frags from global (frag-ordered) ----------------
// grid: 64 g x 6 it x 4 nt = 1536 blocks; tile 96 rows x 256 cols, K=512.

__global__ __launch_bounds__(512) void pool_gemm(
    const float* __restrict__ hpart,     // [1536,512] f32
    const float* __restrict__ curr_pos,  // [1536,2] f32
    const float* __restrict__ Uc,        // [512,2] f32
    const _Float16* __restrict__ W2f,    // fragment-ordered hi/lo (build_w2f)
    const float* __restrict__ bp2,
    _Float16* __restrict__ A_mlp, size_t oPl) {
  __shared__ _Float16 Ah[96][40], Al[96][40];
  __shared__ float Us0[96], Us1[96];
  __shared__ int pool_tile[4][256];
  int b = blockIdx.x;
  int nt = b & 3;
  int it = (b >> 2) % 6;
  int g = b / 24;
  int tid = threadIdx.x;
  int lane = tid & 63, wid = tid >> 6;
  int wm = wid & 1, wn = wid >> 1;  // wm:2, wn:4

  int* pt = &pool_tile[0][0];
  pt[tid] = 0;
  pt[tid + 512] = 0;

  if (tid < 96) {
    int r = tid;
    int i = it * 4 + r / 24;
    int j = r % 24;
    float pix = curr_pos[(g * 24 + i) * 2 + 0];
    float piy = curr_pos[(g * 24 + i) * 2 + 1];
    float dx = curr_pos[(g * 24 + j) * 2 + 0] - pix;
    float dy = curr_pos[(g * 24 + j) * 2 + 1] - piy;
    float nrm = sqrtf(dx * dx + dy * dy);
    float inv = 1.f / fmaxf(nrm, 1e-12f);
    Us0[r] = dx * inv;
    Us1[r] = dy * inv;
  }

  f32x4 acc[3][4];
#pragma unroll
  for (int a = 0; a < 3; a++)
#pragma unroll
    for (int c = 0; c < 4; c++) acc[a][c] = (f32x4){0.f, 0.f, 0.f, 0.f};

  // per-thread build coords: kc fixed, rows r = s*32 + (tid>>4)
  const int kc = (2 * tid) & 31;
  const int rb = tid >> 4;

  for (int c16 = 0; c16 < 16; c16++) {
    const int k0 = c16 * 32;
    // B fragment loads (global, frag-ordered, coalesced 1KB/wave) — no LDS, no barrier dep
    f16x8 bh[4], bl[4];
#pragma unroll
    for (int ni = 0; ni < 4; ni++) {
      int T = nt * 16 + wn * 4 + ni;
      const _Float16* fb = W2f + ((size_t)(T * 16 + c16) * 2 * 64 + lane) * 8;
      bh[ni] = *(const f16x8*)fb;
      bl[ni] = *(const f16x8*)(fb + 512);
    }
    __syncthreads();  // A buffers free (prev reads done); Us ready on first iter
    // build A slice [96][32]
#pragma unroll
    for (int s = 0; s < 3; s++) {
      int r = s * 32 + rb;
      int j = r % 24;
      float2 hp = *(const float2*)(hpart + ((size_t)(g * 24 + j)) * 512 + k0 + kc);
      float4 uc = *(const float4*)(Uc + (size_t)(k0 + kc) * 2);
      float u0 = Us0[r], u1 = Us1[r];
      float v0 = fmaxf(hp.x + u0 * uc.x + u1 * uc.y, 0.f);
      float v1 = fmaxf(hp.y + u0 * uc.z + u1 * uc.w, 0.f);
      _Float16 h0v = (_Float16)v0, h1v = (_Float16)v1;
      _Float16 l0v = (_Float16)(v0 - (float)h0v), l1v = (_Float16)(v1 - (float)h1v);
      *(unsigned int*)&Ah[r][kc] = (unsigned int)h2u(h0v) | ((unsigned int)h2u(h1v) << 16);
      *(unsigned int*)&Al[r][kc] = (unsigned int)h2u(l0v) | ((unsigned int)h2u(l1v) << 16);
    }
    __syncthreads();
    const int kk = (lane >> 4) * 8;
    f16x8 ah[3], al[3];
#pragma unroll
    for (int mi = 0; mi < 3; mi++) {
      int ar = wm * 48 + mi * 16 + (lane & 15);
      ah[mi] = *(const f16x8*)&Ah[ar][kk];
      al[mi] = *(const f16x8*)&Al[ar][kk];
    }
#pragma unroll
    for (int mi = 0; mi < 3; mi++)
#pragma unroll
      for (int ni = 0; ni < 4; ni++) {
        acc[mi][ni] = __builtin_amdgcn_mfma_f32_16x16x32_f16(ah[mi], bh[ni], acc[mi][ni], 0, 0, 0);
        acc[mi][ni] = __builtin_amdgcn_mfma_f32_16x16x32_f16(ah[mi], bl[ni], acc[mi][ni], 0, 0, 0);
        acc[mi][ni] = __builtin_amdgcn_mfma_f32_16x16x32_f16(al[mi], bh[ni], acc[mi][ni], 0, 0, 0);
      }
  }
  __syncthreads();
#pragma unroll
  for (int mi = 0; mi < 3; mi++)
#pragma unroll
    for (int ni = 0; ni < 4; ni++)
#pragma unroll
      for (int r = 0; r < 4; r++) {
        int rl = wm * 48 + mi * 16 + (lane >> 4) * 4 + r;  // 0..95
        int il = rl / 24;                                  // 0..3
        int nl = wn * 64 + ni * 16 + (lane & 15);          // 0..255
        float z = fmaxf(acc[mi][ni][r] + bp2[nt * 256 + nl], 0.f);
        atomicMax(&pool_tile[il][nl], __float_as_int(z));
      }
  __syncthreads();
  for (int idx = tid; idx < 1024; idx += 512) {
    int il = idx >> 8, nl = idx & 255;
    int row = g * 24 + it * 4 + il;
    float z = __int_as_float(pool_tile[il][nl]);
    _Float16 h = (_Float16)z;
    A_mlp[(size_t)row * 1152 + 128 + nt * 256 + nl] = h;
    A_mlp[oPl + (size_t)row * 1152 + 128 + nt * 256 + nl] = (_Float16)(z - (float)h);
  }
}

// ---------------- host ----------------

extern "C" void kernel_launch(void* const* d_in, const int* in_sizes, int n_in,
                              void* d_out, int out_size, void* d_ws, size_t ws_size,
                              hipStream_t stream) {
  (void)in_sizes; (void)n_in; (void)out_size; (void)ws_size;
  const float* last_pos     = (const float*)d_in[0];
  const float* last_pos_rel = (const float*)d_in[1];
  const float* h0    = (const float*)d_in[2];
  const float* c0    = (const float*)d_in[3];
  const float* W_emb = (const float*)d_in[5];
  const float* b_emb = (const float*)d_in[6];
  const float* W_ih  = (const float*)d_in[7];
  const float* W_hh  = (const float*)d_in[8];
  const float* b_ih  = (const float*)d_in[9];
  const float* b_hh  = (const float*)d_in[10];
  const float* W_pos = (const float*)d_in[11];
  const float* b_pos = (const float*)d_in[12];
  const float* Wp_emb = (const float*)d_in[13];
  const float* bp_emb = (const float*)d_in[14];
  const float* Wp1 = (const float*)d_in[15];
  const float* bp1 = (const float*)d_in[16];
  const float* Wp2 = (const float*)d_in[17];
  const float* bp2 = (const float*)d_in[18];
  const float* Wm1 = (const float*)d_in[19];
  const float* bm1 = (const float*)d_in[20];
  const float* Wm2 = (const float*)d_in[21];
  const float* bm2 = (const float*)d_in[22];

  const size_t PL_WG   = 512 * 192;
  const size_t PL_WP1B = 512 * 128;
  const size_t PL_WM1  = (size_t)1024 * 1152;
  const size_t PL_WM2  = (size_t)128 * 1024;
  const size_t PL_AL   = (size_t)1536 * 192;
  const size_t PL_AM   = (size_t)1536 * 1152;
  const size_t PL_DH   = (size_t)1536 * 1024;

  char* ws = (char*)d_ws;
  size_t off = 0;
  auto alloc = [&](size_t bytes) -> void* {
    void* p = ws + off;
    off = (off + bytes + 255) & ~(size_t)255;
    return p;
  };
  _Float16* Wg_s   = (_Float16*)alloc(PL_WG * 2 * 2);
  _Float16* Wp1b_s = (_Float16*)alloc(PL_WP1B * 2 * 2);
  _Float16* W2f    = (_Float16*)alloc((size_t)1024 * 512 * 2 * 2);  // frag-ordered hi/lo
  _Float16* Wm1_s  = (_Float16*)alloc(PL_WM1 * 2 * 2);
  _Float16* Wm2_s  = (_Float16*)alloc(PL_WM2 * 2 * 2);
  float* Uc     = (float*)alloc(512 * 2 * 4);
  float* c1     = (float*)alloc(512 * 4);
  float* bias_g = (float*)alloc(512 * 4);
  _Float16* A_lstm = (_Float16*)alloc(PL_AL * 2 * 2);
  float* gates   = (float*)alloc((size_t)1536 * 512 * 4);
  float* c_state = (float*)alloc((size_t)1536 * 128 * 4);
  _Float16* A_mlp = (_Float16*)alloc(PL_AM * 2 * 2);
  float* curr_pos = (float*)alloc(1536 * 2 * 4);
  float* hpart = (float*)alloc((size_t)1536 * 512 * 4);
  _Float16* dh = (_Float16*)alloc(PL_DH * 2 * 2);

  float* rels = (float*)d_out;                      // [12,1536,2]
  float* h_out = ((float*)d_out) + 12 * 1536 * 2;   // [1536,128]

  // ---- init weights + state ----
  build_w2f<<<256, 256, 0, stream>>>(Wp2, W2f);
  cvt_split<<<(1179648 + 255) / 256, 256, 0, stream>>>(Wm1, Wm1_s, 1179648);
  cvt_split<<<(131072 + 255) / 256, 256, 0, stream>>>(Wm2, Wm2_s, 131072);
  build_wg<<<(512 * 192 + 255) / 256, 256, 0, stream>>>(W_ih, W_hh, Wg_s);
  build_wp1b<<<(512 * 128 + 255) / 256, 256, 0, stream>>>(Wp1, Wp1b_s);
  build_misc<<<2, 256, 0, stream>>>(Wp1, Wp_emb, bp_emb, bp1, b_ih, b_hh, Uc, c1, bias_g);
  init_state<<<1536, 192, 0, stream>>>(last_pos, last_pos_rel, h0, c0, W_emb, b_emb,
                                       A_lstm, PL_AL, c_state, curr_pos);

  for (int t = 0; t < 12; t++) {
    gemm_f16s<<<dim3(24, 8), 256, 0, stream>>>(A_lstm, PL_AL, 192, Wg_s, PL_WG, 192, bias_g,
                                               gates, 512, (_Float16*)nullptr, 0, 0, 192, 0);
    lstm_pointwise<<<96, 256, 0, stream>>>(gates, c_state, A_mlp, PL_AM, curr_pos,
                                           rels + (size_t)t * 1536 * 2, A_lstm, PL_AL,
                                           W_pos, b_pos, W_emb, b_emb);
    gemm_f16s<<<dim3(24, 8), 256, 0, stream>>>(A_mlp, PL_AM, 1152, Wp1b_s, PL_WP1B, 128, c1,
                                               hpart, 512, (_Float16*)nullptr, 0, 0, 128, 0);
    pool_gemm<<<1536, 512, 0, stream>>>(hpart, curr_pos, Uc, W2f, bp2, A_mlp, PL_AM);
    gemm_f16s<<<dim3(24, 16), 256, 0, stream>>>(A_mlp, PL_AM, 1152, Wm1_s, PL_WM1, 1152, bm1,
                                                (float*)nullptr, 0, dh, PL_DH, 1024, 1152, 1);
    float* houtF = (t == 11) ? h_out : (float*)nullptr;
    gemm_f16s<<<dim3(24, 2), 256, 0, stream>>>(dh, PL_DH, 1024, Wm2_s, PL_WM2, 1024, bm2,
                                               houtF, 128, A_lstm + 64, PL_AL, 192, 1024, 1);
  }
}